// Round 1
// baseline (3077.354 us; speedup 1.0000x reference)
//
#include <hip/hip_runtime.h>

#define N_NODES 10000
#define B 8
#define T_STEPS 12
#define E_EDGES 160000
#define HG 64
#define HR 64
#define P_OUT 12
#define BN (B * N_NODES)   // 80000

// ---------------- GCN normalization + aggregation ----------------

__global__ void deg_kernel(const int* __restrict__ ei, const float* __restrict__ ew,
                           float* __restrict__ deg) {
    int e = blockIdx.x * blockDim.x + threadIdx.x;
    if (e < E_EDGES) atomicAdd(&deg[ei[E_EDGES + e]], ew[e]);
}

__global__ void dinv_kernel(float* __restrict__ deg) {
    int n = blockIdx.x * blockDim.x + threadIdx.x;
    if (n < N_NODES) deg[n] = rsqrtf(deg[n] + 1.0f);   // +1 = self-loop weight
}

// Self-loop contribution: aggS[t*BN + b*N + n] = dinv[n]^2 * x[b,n,t]
__global__ void self_kernel(const float* __restrict__ x, const float* __restrict__ dinv,
                            float* __restrict__ aggS) {
    int tid = blockIdx.x * blockDim.x + threadIdx.x;
    if (tid >= BN * T_STEPS) return;
    int n = tid % N_NODES;
    int b = (tid / N_NODES) % B;
    int t = tid / BN;
    float di = dinv[n];
    aggS[tid] = di * di * x[(b * N_NODES + n) * T_STEPS + t];
}

// Edge contribution: one thread per (edge, b); 12 atomics (one per t)
__global__ void edge_kernel(const int* __restrict__ ei, const float* __restrict__ ew,
                            const float* __restrict__ dinv, const float* __restrict__ x,
                            float* __restrict__ aggS) {
    int tid = blockIdx.x * blockDim.x + threadIdx.x;
    if (tid >= E_EDGES * B) return;
    int e = tid % E_EDGES;
    int b = tid / E_EDGES;
    int s = ei[e];
    int d = ei[E_EDGES + e];
    float norm = dinv[s] * ew[e] * dinv[d];
    // (b*N+s)*12 floats = 48B offset -> 16B aligned, safe for float4
    const float4* xp = reinterpret_cast<const float4*>(&x[(b * N_NODES + s) * T_STEPS]);
    float4 x0 = xp[0], x1 = xp[1], x2 = xp[2];
    float* dst = &aggS[b * N_NODES + d];
    atomicAdd(dst + 0 * BN,  norm * x0.x);
    atomicAdd(dst + 1 * BN,  norm * x0.y);
    atomicAdd(dst + 2 * BN,  norm * x0.z);
    atomicAdd(dst + 3 * BN,  norm * x0.w);
    atomicAdd(dst + 4 * BN,  norm * x1.x);
    atomicAdd(dst + 5 * BN,  norm * x1.y);
    atomicAdd(dst + 6 * BN,  norm * x1.z);
    atomicAdd(dst + 7 * BN,  norm * x1.w);
    atomicAdd(dst + 8 * BN,  norm * x2.x);
    atomicAdd(dst + 9 * BN,  norm * x2.y);
    atomicAdd(dst + 10 * BN, norm * x2.z);
    atomicAdd(dst + 11 * BN, norm * x2.w);
}

// ---------------- Fused GRU + output head ----------------

__device__ __forceinline__ float fast_rcp(float v) { return __builtin_amdgcn_rcpf(v); }
__device__ __forceinline__ float sigmoid_f(float v) { return fast_rcp(1.0f + __expf(-v)); }
__device__ __forceinline__ float tanh_f(float v) {
    // 2/(1+exp(-2v)) - 1 ; exp overflow -> rcp(inf)=0 -> -1, correct saturation
    float e = __expf(-2.0f * v);
    return fmaf(2.0f, fast_rcp(1.0f + e), -1.0f);
}

// One thread per sequence. h, xt live in registers; the h-update (register-
// indexed write) routes through a per-thread-private LDS column ([j][tid]
// layout: lane-consecutive -> bank-conflict-free; no barrier needed).
// Weight reads are wave-uniform -> expect scalar loads from K$/L2 (96 KB,
// fully L2-resident).
__global__ __launch_bounds__(64) void gru_kernel(
    const float* __restrict__ aggS,
    const float* __restrict__ gW, const float* __restrict__ gb,
    const float* __restrict__ Wih, const float* __restrict__ Whh,
    const float* __restrict__ bih, const float* __restrict__ bhh,
    const float* __restrict__ Wout, const float* __restrict__ bout,
    float* __restrict__ out)
{
    __shared__ float hbuf[64 * 64];   // 16 KB
    const int tid = threadIdx.x;
    const int bn = blockIdx.x * 64 + tid;   // BN = 1250*64 exactly, no bounds check

    float h[64];
#pragma unroll
    for (int k = 0; k < 64; k++) h[k] = 0.0f;

#pragma unroll 1
    for (int t = 0; t < T_STEPS; t++) {
        const float a = aggS[t * BN + bn];
        float xt[64];
#pragma unroll
        for (int k = 0; k < 64; k++) xt[k] = fmaxf(fmaf(a, gW[k], gb[k]), 0.0f);

#pragma unroll 1
        for (int j = 0; j < 64; j++) {
            float air = bih[j], aiz = bih[j + 64], ain = bih[j + 128];
            float ahr = bhh[j], ahz = bhh[j + 64], ahn = bhh[j + 128];
            const float* wr = &Wih[j * 64];
            const float* wz = &Wih[(j + 64) * 64];
            const float* wn = &Wih[(j + 128) * 64];
            const float* vr = &Whh[j * 64];
            const float* vz = &Whh[(j + 64) * 64];
            const float* vn = &Whh[(j + 128) * 64];
#pragma unroll
            for (int k = 0; k < 64; k++) {
                const float xk = xt[k], hk = h[k];
                air = fmaf(wr[k], xk, air);
                aiz = fmaf(wz[k], xk, aiz);
                ain = fmaf(wn[k], xk, ain);
                ahr = fmaf(vr[k], hk, ahr);
                ahz = fmaf(vz[k], hk, ahz);
                ahn = fmaf(vn[k], hk, ahn);
            }
            float r = sigmoid_f(air + ahr);
            float z = sigmoid_f(aiz + ahz);
            float nn = tanh_f(fmaf(r, ahn, ain));
            hbuf[j * 64 + tid] = (1.0f - z) * nn + z * h[j];
        }
        // per-thread private RAW on LDS: compiler inserts lgkmcnt wait, no barrier
#pragma unroll
        for (int k = 0; k < 64; k++) h[k] = hbuf[k * 64 + tid];
    }

    // output head: pred[bn, p] = b_out[p] + sum_k Wout[p,k] * h[k]
#pragma unroll 1
    for (int p = 0; p < P_OUT; p++) {
        float acc = bout[p];
#pragma unroll
        for (int k = 0; k < 64; k++) acc = fmaf(Wout[p * 64 + k], h[k], acc);
        out[(long)bn * P_OUT + p] = acc;
    }
}

// ---------------- launcher ----------------

extern "C" void kernel_launch(void* const* d_in, const int* in_sizes, int n_in,
                              void* d_out, int out_size, void* d_ws, size_t ws_size,
                              hipStream_t stream)
{
    const float* x    = (const float*)d_in[0];
    const int*   ei   = (const int*)  d_in[1];
    const float* ew   = (const float*)d_in[2];
    const float* gW   = (const float*)d_in[3];
    const float* gb   = (const float*)d_in[4];
    const float* Wih  = (const float*)d_in[5];
    const float* Whh  = (const float*)d_in[6];
    const float* bih  = (const float*)d_in[7];
    const float* bhh  = (const float*)d_in[8];
    const float* Wout = (const float*)d_in[9];
    const float* bout = (const float*)d_in[10];
    float* out = (float*)d_out;

    float* deg  = (float*)d_ws;          // N floats (becomes dinv in-place)
    float* aggS = deg + N_NODES;         // BN*T floats

    hipMemsetAsync(deg, 0, N_NODES * sizeof(float), stream);
    deg_kernel<<<(E_EDGES + 255) / 256, 256, 0, stream>>>(ei, ew, deg);
    dinv_kernel<<<(N_NODES + 255) / 256, 256, 0, stream>>>(deg);
    self_kernel<<<(BN * T_STEPS + 255) / 256, 256, 0, stream>>>(x, deg, aggS);
    edge_kernel<<<(E_EDGES * B + 255) / 256, 256, 0, stream>>>(ei, ew, deg, x, aggS);
    gru_kernel<<<BN / 64, 64, 0, stream>>>(aggS, gW, gb, Wih, Whh, bih, bhh,
                                           Wout, bout, out);
}

// Round 2
// 2927.828 us; speedup vs baseline: 1.0511x; 1.0511x over previous
//
#include <hip/hip_runtime.h>

#define N_NODES 10000
#define B 8
#define T_STEPS 12
#define E_EDGES 160000
#define HG 64
#define HR 64
#define P_OUT 12
#define BN (B * N_NODES)   // 80000

// ---------------- GCN normalization + aggregation ----------------

__global__ void deg_kernel(const int* __restrict__ ei, const float* __restrict__ ew,
                           float* __restrict__ deg) {
    int e = blockIdx.x * blockDim.x + threadIdx.x;
    if (e < E_EDGES) atomicAdd(&deg[ei[E_EDGES + e]], ew[e]);
}

__global__ void dinv_kernel(float* __restrict__ deg) {
    int n = blockIdx.x * blockDim.x + threadIdx.x;
    if (n < N_NODES) deg[n] = rsqrtf(deg[n] + 1.0f);   // +1 = self-loop weight
}

// Self-loop contribution: aggS[t*BN + b*N + n] = dinv[n]^2 * x[b,n,t]
__global__ void self_kernel(const float* __restrict__ x, const float* __restrict__ dinv,
                            float* __restrict__ aggS) {
    int tid = blockIdx.x * blockDim.x + threadIdx.x;
    if (tid >= BN * T_STEPS) return;
    int n = tid % N_NODES;
    int b = (tid / N_NODES) % B;
    int t = tid / BN;
    float di = dinv[n];
    aggS[tid] = di * di * x[(b * N_NODES + n) * T_STEPS + t];
}

// Edge contribution: one thread per (edge, b); 12 atomics (one per t)
__global__ void edge_kernel(const int* __restrict__ ei, const float* __restrict__ ew,
                            const float* __restrict__ dinv, const float* __restrict__ x,
                            float* __restrict__ aggS) {
    int tid = blockIdx.x * blockDim.x + threadIdx.x;
    if (tid >= E_EDGES * B) return;
    int e = tid % E_EDGES;
    int b = tid / E_EDGES;
    int s = ei[e];
    int d = ei[E_EDGES + e];
    float norm = dinv[s] * ew[e] * dinv[d];
    // (b*N+s)*12 floats = 48B offset -> 16B aligned, safe for float4
    const float4* xp = reinterpret_cast<const float4*>(&x[(b * N_NODES + s) * T_STEPS]);
    float4 x0 = xp[0], x1 = xp[1], x2 = xp[2];
    float* dst = &aggS[b * N_NODES + d];
    atomicAdd(dst + 0 * BN,  norm * x0.x);
    atomicAdd(dst + 1 * BN,  norm * x0.y);
    atomicAdd(dst + 2 * BN,  norm * x0.z);
    atomicAdd(dst + 3 * BN,  norm * x0.w);
    atomicAdd(dst + 4 * BN,  norm * x1.x);
    atomicAdd(dst + 5 * BN,  norm * x1.y);
    atomicAdd(dst + 6 * BN,  norm * x1.z);
    atomicAdd(dst + 7 * BN,  norm * x1.w);
    atomicAdd(dst + 8 * BN,  norm * x2.x);
    atomicAdd(dst + 9 * BN,  norm * x2.y);
    atomicAdd(dst + 10 * BN, norm * x2.z);
    atomicAdd(dst + 11 * BN, norm * x2.w);
}

// ---------------- Fused GRU + output head ----------------

__device__ __forceinline__ float fast_rcp(float v) { return __builtin_amdgcn_rcpf(v); }
__device__ __forceinline__ float sigmoid_f(float v) { return fast_rcp(1.0f + __expf(-v)); }
__device__ __forceinline__ float tanh_f(float v) {
    // 2/(1+exp(-2v)) - 1 ; exp overflow -> rcp(inf)=0 -> -1, correct saturation
    float e = __expf(-2.0f * v);
    return fmaf(2.0f, fast_rcp(1.0f + e), -1.0f);
}

// One thread per sequence. h (prev step) and xt live in registers with ONLY
// static indexing (fully unrolled k-loops) -> no scratch demotion. The one
// dynamically-indexed h access (h_prev[j] in the j-loop) reads the LDS column
// hbuf[j*64+tid], which still holds h_{t-1}[j] at that point; the new h_t[j]
// overwrites it, and after the j-loop the column is copied back into the h
// registers with static indexing. [j][tid] layout: lane==bank, conflict-free,
// per-thread-private column so no barrier needed.
__global__ __launch_bounds__(64) void gru_kernel(
    const float* __restrict__ aggS,
    const float* __restrict__ gW, const float* __restrict__ gb,
    const float* __restrict__ Wih, const float* __restrict__ Whh,
    const float* __restrict__ bih, const float* __restrict__ bhh,
    const float* __restrict__ Wout, const float* __restrict__ bout,
    float* __restrict__ out)
{
    __shared__ float hbuf[64 * 64];   // 16 KB
    const int tid = threadIdx.x;
    const int bn = blockIdx.x * 64 + tid;   // BN = 1250*64 exactly, no bounds check

    float h[64];
#pragma unroll
    for (int k = 0; k < 64; k++) h[k] = 0.0f;
#pragma unroll
    for (int k = 0; k < 64; k++) hbuf[k * 64 + tid] = 0.0f;

#pragma unroll 1
    for (int t = 0; t < T_STEPS; t++) {
        const float a = aggS[t * BN + bn];
        float xt[64];
#pragma unroll
        for (int k = 0; k < 64; k++) xt[k] = fmaxf(fmaf(a, gW[k], gb[k]), 0.0f);

#pragma unroll 1
        for (int j = 0; j < 64; j++) {
            float air = bih[j], aiz = bih[j + 64], ain = bih[j + 128];
            float ahr = bhh[j], ahz = bhh[j + 64], ahn = bhh[j + 128];
            const float* wr = &Wih[j * 64];
            const float* wz = &Wih[(j + 64) * 64];
            const float* wn = &Wih[(j + 128) * 64];
            const float* vr = &Whh[j * 64];
            const float* vz = &Whh[(j + 64) * 64];
            const float* vn = &Whh[(j + 128) * 64];
#pragma unroll
            for (int k = 0; k < 64; k++) {
                const float xk = xt[k], hk = h[k];
                air = fmaf(wr[k], xk, air);
                aiz = fmaf(wz[k], xk, aiz);
                ain = fmaf(wn[k], xk, ain);
                ahr = fmaf(vr[k], hk, ahr);
                ahz = fmaf(vz[k], hk, ahz);
                ahn = fmaf(vn[k], hk, ahn);
            }
            float r = sigmoid_f(air + ahr);
            float z = sigmoid_f(aiz + ahz);
            float nn = tanh_f(fmaf(r, ahn, ain));
            // previous h[j] still lives in the LDS column (not yet overwritten)
            float hprev_j = hbuf[j * 64 + tid];
            hbuf[j * 64 + tid] = (1.0f - z) * nn + z * hprev_j;
        }
        // per-thread private RAW on LDS: compiler inserts lgkmcnt wait, no barrier
#pragma unroll
        for (int k = 0; k < 64; k++) h[k] = hbuf[k * 64 + tid];
    }

    // output head: pred[bn, p] = b_out[p] + sum_k Wout[p,k] * h[k]
#pragma unroll 1
    for (int p = 0; p < P_OUT; p++) {
        float acc = bout[p];
#pragma unroll
        for (int k = 0; k < 64; k++) acc = fmaf(Wout[p * 64 + k], h[k], acc);
        out[(long)bn * P_OUT + p] = acc;
    }
}

// ---------------- launcher ----------------

extern "C" void kernel_launch(void* const* d_in, const int* in_sizes, int n_in,
                              void* d_out, int out_size, void* d_ws, size_t ws_size,
                              hipStream_t stream)
{
    const float* x    = (const float*)d_in[0];
    const int*   ei   = (const int*)  d_in[1];
    const float* ew   = (const float*)d_in[2];
    const float* gW   = (const float*)d_in[3];
    const float* gb   = (const float*)d_in[4];
    const float* Wih  = (const float*)d_in[5];
    const float* Whh  = (const float*)d_in[6];
    const float* bih  = (const float*)d_in[7];
    const float* bhh  = (const float*)d_in[8];
    const float* Wout = (const float*)d_in[9];
    const float* bout = (const float*)d_in[10];
    float* out = (float*)d_out;

    float* deg  = (float*)d_ws;          // N floats (becomes dinv in-place)
    float* aggS = deg + N_NODES;         // BN*T floats

    hipMemsetAsync(deg, 0, N_NODES * sizeof(float), stream);
    deg_kernel<<<(E_EDGES + 255) / 256, 256, 0, stream>>>(ei, ew, deg);
    dinv_kernel<<<(N_NODES + 255) / 256, 256, 0, stream>>>(deg);
    self_kernel<<<(BN * T_STEPS + 255) / 256, 256, 0, stream>>>(x, deg, aggS);
    edge_kernel<<<(E_EDGES * B + 255) / 256, 256, 0, stream>>>(ei, ew, deg, x, aggS);
    gru_kernel<<<BN / 64, 64, 0, stream>>>(aggS, gW, gb, Wih, Whh, bih, bhh,
                                           Wout, bout, out);
}